// Round 1
// 1010.239 us; speedup vs baseline: 1.0771x; 1.0771x over previous
//
#include <hip/hip_runtime.h>

#define N_RES   20000
#define N_EDGE  640000
#define NFEAT   340

// freq[m] = exp(2m * (-ln(10000)/16)) = 10^(-m/2)
__device__ __constant__ float c_freq[8] = {
    1.0f, 0.31622776601683794f, 0.1f, 0.031622776601683794f,
    0.01f, 0.0031622776601683794f, 0.001f, 0.00031622776601683794f};

// Per-residue precompute: bb[12] (N,CA,C,virtual CB), local[12] = R^T(bb-t),
// R[9], t[3]  -> 36 floats per residue in workspace.
extern "C" __global__ __launch_bounds__(256)
void residue_prep(const float* __restrict__ atom14,
                  const float* __restrict__ rigids7,
                  float* __restrict__ res) {
    int r = blockIdx.x * 256 + threadIdx.x;
    if (r >= N_RES) return;

    const float* a = atom14 + (size_t)r * 42;  // 14 atoms * 3
    float nx  = a[0], ny  = a[1], nz  = a[2];
    float cax = a[3], cay = a[4], caz = a[5];
    float cx  = a[6], cy  = a[7], cz  = a[8];

    // virtual CB
    float bx = cax - nx, by = cay - ny, bz = caz - nz;     // b  = ca - n
    float ex = cx - cax, ey = cy - cay, ez = cz - caz;     // cc = c - ca
    float ax = by * ez - bz * ey;                          // a = cross(b, cc)
    float ay = bz * ex - bx * ez;
    float az = bx * ey - by * ex;
    float cbx = -0.58273431f * ax + 0.56802827f * bx - 0.54067466f * ex + cax;
    float cby = -0.58273431f * ay + 0.56802827f * by - 0.54067466f * ey + cay;
    float cbz = -0.58273431f * az + 0.56802827f * bz - 0.54067466f * ez + caz;

    const float* q7 = rigids7 + (size_t)r * 7;
    float qw = q7[0], qx = q7[1], qy = q7[2], qz = q7[3];
    float inv = 1.0f / sqrtf(qw * qw + qx * qx + qy * qy + qz * qz);
    qw *= inv; qx *= inv; qy *= inv; qz *= inv;
    float tx = q7[4], ty = q7[5], tz = q7[6];

    // R[j*3+i] : row j, col i (matches _quat_to_rot stacking)
    float R[9];
    R[0] = 1.0f - 2.0f * (qy * qy + qz * qz);
    R[1] = 2.0f * (qx * qy - qw * qz);
    R[2] = 2.0f * (qx * qz + qw * qy);
    R[3] = 2.0f * (qx * qy + qw * qz);
    R[4] = 1.0f - 2.0f * (qx * qx + qz * qz);
    R[5] = 2.0f * (qy * qz - qw * qx);
    R[6] = 2.0f * (qx * qz - qw * qy);
    R[7] = 2.0f * (qy * qz + qw * qx);
    R[8] = 1.0f - 2.0f * (qx * qx + qy * qy);

    float bb[12] = {nx, ny, nz, cax, cay, caz, cx, cy, cz, cbx, cby, cbz};

    float* o = res + (size_t)r * 36;
    #pragma unroll
    for (int k = 0; k < 12; ++k) o[k] = bb[k];
    // local[k][i] = sum_j R[j][i] * (bb[k][j] - t[j])   (R^T * x)
    #pragma unroll
    for (int k = 0; k < 4; ++k) {
        float x0 = bb[k * 3 + 0] - tx;
        float x1 = bb[k * 3 + 1] - ty;
        float x2 = bb[k * 3 + 2] - tz;
        #pragma unroll
        for (int i = 0; i < 3; ++i)
            o[12 + k * 3 + i] = R[i] * x0 + R[3 + i] * x1 + R[6 + i] * x2;
    }
    #pragma unroll
    for (int j = 0; j < 9; ++j) o[24 + j] = R[j];
    o[33] = tx; o[34] = ty; o[35] = tz;
}

// Positional-encoding table: dpos = dst-src is an INTEGER in [-19999,19999].
// tab[row][0..7] = cos(d*freq[m]), tab[row][8..15] = sin(d*freq[m]), d = row-19999.
// Uses the exact same cosf/sinf expressions as the previous passing kernel ->
// bitwise-identical pos features (absmax stays at 0.125).
extern "C" __global__ __launch_bounds__(256)
void pos_table(float* __restrict__ tab) {
    int idx = blockIdx.x * 256 + threadIdx.x;   // 0 .. 640000-1 (40000 rows * 16)
    int row = idx >> 4;
    int m = idx & 15;
    float d = (float)(row - 19999);
    float ang = d * c_freq[m & 7];
    tab[idx] = (m < 8) ? cosf(ang) : sinf(ang);
}

// One wave (64 lanes) per edge, 4 waves / 256-thread block.
// Phase 1: 64 lanes each own one float4 RBF chunk (f = 44+4l .. 47+4l) ->
//          pair = l>>2 is lane-local, NO shuffle; one dwordx4 store per lane.
// Phase 2: lanes 0-43 one-hots/flags (dword), 44-55 dst_in_src dots (dword),
//          56-59 pos-enc float4 (table load), 60-62 src-local float4.
extern "C" __global__ __launch_bounds__(256)
void edge_feats(const int* __restrict__ eidx,
                const int* __restrict__ seq,
                const int* __restrict__ mask,
                const float* __restrict__ res,
                const float* __restrict__ postab,
                float* __restrict__ out) {
    int lane = threadIdx.x & 63;
    int wave = threadIdx.x >> 6;
    int e = __builtin_amdgcn_readfirstlane((int)(blockIdx.x * 4 + wave));

    int dst = eidx[e];
    int src = eidx[N_EDGE + e];
    int msrc = mask[src];
    int mdst = mask[dst];
    float noised_src = msrc ? 1.0f : 0.0f;
    float noised_dst = mdst ? 1.0f : 0.0f;
    float keep_src = 1.0f - noised_src;
    float keep_dst = 1.0f - noised_dst;
    int ssrc = seq[src];
    int sdst = seq[dst];

    const float* rs = res + (size_t)src * 36;
    const float* rd = res + (size_t)dst * 36;
    float* op = out + (size_t)e * NFEAT;

    // ---------------- Phase 1: RBF block, f = 44 .. 299 ----------------
    {
        int ai = lane >> 4;          // src atom 0..3
        int aj = (lane >> 2) & 3;    // dst atom 0..3
        const float* sp = rs + ai * 3;
        const float* dp = rd + aj * 3;
        float dx = sp[0] - dp[0] + 1e-8f;
        float dy = sp[1] - dp[1] + 1e-8f;
        float dz = sp[2] - dp[2] + 1e-8f;
        float D = sqrtf(dx * dx + dy * dy + dz * dz);

        int rbase = (lane & 3) * 4;
        float4 v;
        float x;
        float mu;
        mu = 2.0f + (20.0f / 15.0f) * (float)(rbase + 0);
        x = (D - mu) * 0.8f;  v.x = __expf(-x * x);
        mu = 2.0f + (20.0f / 15.0f) * (float)(rbase + 1);
        x = (D - mu) * 0.8f;  v.y = __expf(-x * x);
        mu = 2.0f + (20.0f / 15.0f) * (float)(rbase + 2);
        x = (D - mu) * 0.8f;  v.z = __expf(-x * x);
        mu = 2.0f + (20.0f / 15.0f) * (float)(rbase + 3);
        x = (D - mu) * 0.8f;  v.w = __expf(-x * x);

        *reinterpret_cast<float4*>(op + 44 + 4 * lane) = v;  // 16B-aligned: 1360e+176+16l
    }

    // ---------------- Phase 2: remaining 84 features ----------------
    if (lane < 44) {
        // f = lane : [noised_dst, noised_src, src one-hot(21), dst one-hot(21)]
        float v = (lane < 23) ? ((ssrc == lane - 2) ? keep_src : 0.0f)
                              : ((sdst == lane - 23) ? keep_dst : 0.0f);
        if (lane == 0) v = noised_dst;
        if (lane == 1) v = noised_src;
        op[lane] = v;
    } else if (lane < 56) {
        // dst_in_src[qq], qq = lane-44 : k = qq/3 (atom), i = qq%3 (col)
        int qq = lane - 44;
        int k = qq / 3;
        int i2 = qq - k * 3;
        float t0 = rs[33], t1 = rs[34], t2 = rs[35];     // wave-uniform (scalar)
        float x0 = rd[k * 3 + 0] - t0;
        float x1 = rd[k * 3 + 1] - t1;
        float x2 = rd[k * 3 + 2] - t2;
        float v = (rs[24 + i2] * x0 + rs[27 + i2] * x1 + rs[30 + i2] * x2) * keep_dst;
        op[328 + qq] = v;
    } else if (lane < 60) {
        // positional encoding, f = 300..315, from precomputed table (one 64B row)
        int c = lane - 56;
        const float4 v = *reinterpret_cast<const float4*>(
            postab + ((size_t)(dst - src + 19999) * 16 + c * 4));
        *reinterpret_cast<float4*>(op + 300 + 4 * c) = v;
    } else if (lane < 63) {
        // src_bb_local * keep_src, f = 316..327
        int c = lane - 60;
        float4 v = *reinterpret_cast<const float4*>(rs + 12 + 4 * c);
        v.x *= keep_src; v.y *= keep_src; v.z *= keep_src; v.w *= keep_src;
        *reinterpret_cast<float4*>(op + 316 + 4 * c) = v;
    }
}

extern "C" void kernel_launch(void* const* d_in, const int* in_sizes, int n_in,
                              void* d_out, int out_size, void* d_ws, size_t ws_size,
                              hipStream_t stream) {
    const float* atom14  = (const float*)d_in[0];
    const float* rigids7 = (const float*)d_in[1];
    const int* seq  = (const int*)d_in[2];
    const int* mask = (const int*)d_in[3];
    const int* eidx = (const int*)d_in[4];
    float* res = (float*)d_ws;           // 20000*36 floats = 2.88 MB
    float* tab = res + 720000;           // 40000*16 floats = 2.56 MB (ws total 5.44 MB)

    hipLaunchKernelGGL(residue_prep, dim3((N_RES + 255) / 256), dim3(256), 0, stream,
                       atom14, rigids7, res);
    hipLaunchKernelGGL(pos_table, dim3(2500), dim3(256), 0, stream, tab);
    hipLaunchKernelGGL(edge_feats, dim3(N_EDGE / 4), dim3(256), 0, stream,
                       eidx, seq, mask, res, tab, (float*)d_out);
}